// Round 2
// baseline (875.904 us; speedup 1.0000x reference)
//
#include <hip/hip_runtime.h>
#include <hip/hip_bf16.h>

#define TK 8192
#define HD 1024
#define NE 64
#define TOPK 2
#define CAP 1024
#define FD 512
#define SFD 1024

typedef unsigned short u16;
typedef unsigned int u32;
typedef short bf16x8 __attribute__((ext_vector_type(8)));
typedef float f32x4 __attribute__((ext_vector_type(4)));

#define M_EXP1 0
#define M_EXP2 1
#define M_SH1  2
#define M_SH2  3

__device__ __forceinline__ float bf2f(u16 b){
  u32 u = ((u32)b) << 16;
  return __uint_as_float(u);
}
__device__ __forceinline__ u16 f2bf(float f){
  u32 u = __float_as_uint(f);
  u32 r = (u + 0x7fffu + ((u >> 16) & 1u)) >> 16;
  return (u16)r;
}
__device__ __forceinline__ float gelu_tanh(float x){
  float x3 = x * x * x;
  float t = tanhf(0.7978845608028654f * (x + 0.044715f * x3));
  return 0.5f * x * (1.0f + t);
}

// async global->LDS, 16B per lane; LDS dest = wave-uniform base + lane*16
typedef __attribute__((address_space(1))) const u32 gu32;
typedef __attribute__((address_space(3))) u32 lu32;
__device__ __forceinline__ void gload_lds16(const void* g, void* l){
  gu32* gp = (gu32*)(unsigned long long)(uintptr_t)g;
  lu32* lp = (lu32*)(u32)(uintptr_t)l;
  __builtin_amdgcn_global_load_lds(gp, lp, 16, 0, 0);
}

// ---------------- prep: cast x to bf16 ----------------
__global__ __launch_bounds__(256) void cast_x_kernel(const float* __restrict__ x,
                                                     u16* __restrict__ xbf){
  size_t i = ((size_t)blockIdx.x * 256 + threadIdx.x) * 4;
  float4 v = *(const float4*)&x[i];
  ushort4 o;
  o.x = f2bf(v.x); o.y = f2bf(v.y); o.z = f2bf(v.z); o.w = f2bf(v.w);
  *(ushort4*)&xbf[i] = o;
}

// ---------------- prep: batched transpose fp32 [B,R,C] -> bf16 [B,C,R] ----------------
__global__ __launch_bounds__(256) void transpose_cast(const float* __restrict__ src,
                                                      u16* __restrict__ dst,
                                                      int R, int C){
  __shared__ float tile[64][65];
  const int c0 = blockIdx.x * 64, r0 = blockIdx.y * 64;
  const size_t bb = (size_t)blockIdx.z * R * C;
  const int tid = threadIdx.x;
  const int tr = tid >> 4, tc = (tid & 15) * 4;
#pragma unroll
  for (int i = 0; i < 4; i++){
    float4 v = *(const float4*)&src[bb + (size_t)(r0 + tr + i * 16) * C + c0 + tc];
    tile[tr + i * 16][tc + 0] = v.x;
    tile[tr + i * 16][tc + 1] = v.y;
    tile[tr + i * 16][tc + 2] = v.z;
    tile[tr + i * 16][tc + 3] = v.w;
  }
  __syncthreads();
#pragma unroll
  for (int i = 0; i < 4; i++){
    int dr = tr + i * 16;
    ushort4 o;
    o.x = f2bf(tile[tc + 0][dr]);
    o.y = f2bf(tile[tc + 1][dr]);
    o.z = f2bf(tile[tc + 2][dr]);
    o.w = f2bf(tile[tc + 3][dr]);
    *(ushort4*)&dst[bb + (size_t)(c0 + dr) * R + r0 + tc] = o;
  }
}

// ---------------- router GEMM (fp32, deterministic K-split partials) ----------------
__global__ __launch_bounds__(256) void router_gemm(const float* __restrict__ X,
                                                   const float* __restrict__ Wr,
                                                   float* __restrict__ part){
  __shared__ float Xs[32][36];
  __shared__ float Ws[32][64];
  const int t0 = blockIdx.x * 32;
  const int kh = blockIdx.y;
  const int tid = threadIdx.x;
  const int tx = tid & 15, ty = tid >> 4;
  float acc[2][4] = {};
  for (int k0 = kh * 512; k0 < kh * 512 + 512; k0 += 32){
    {
      int c = tid; int r = c >> 3, cc = (c & 7) * 4;
      *(float4*)&Xs[r][cc] = *(const float4*)&X[(size_t)(t0 + r) * HD + k0 + cc];
    }
#pragma unroll
    for (int i = 0; i < 2; i++){
      int c = tid + i * 256; int r = c >> 4, cc = (c & 15) * 4;
      *(float4*)&Ws[r][cc] = *(const float4*)&Wr[(size_t)(k0 + r) * NE + cc];
    }
    __syncthreads();
#pragma unroll
    for (int kk = 0; kk < 32; kk += 4){
      float a[2][4], b[4][4];
#pragma unroll
      for (int i = 0; i < 2; i++){
        float4 v = *(const float4*)&Xs[ty * 2 + i][kk];
        a[i][0] = v.x; a[i][1] = v.y; a[i][2] = v.z; a[i][3] = v.w;
      }
#pragma unroll
      for (int q = 0; q < 4; q++){
        float4 v = *(const float4*)&Ws[kk + q][tx * 4];
        b[q][0] = v.x; b[q][1] = v.y; b[q][2] = v.z; b[q][3] = v.w;
      }
#pragma unroll
      for (int i = 0; i < 2; i++)
#pragma unroll
        for (int j = 0; j < 4; j++)
          acc[i][j] += a[i][0]*b[0][j] + a[i][1]*b[1][j] + a[i][2]*b[2][j] + a[i][3]*b[3][j];
    }
    __syncthreads();
  }
#pragma unroll
  for (int i = 0; i < 2; i++){
    float4 o; o.x = acc[i][0]; o.y = acc[i][1]; o.z = acc[i][2]; o.w = acc[i][3];
    *(float4*)&part[(size_t)kh * TK * NE + (size_t)(t0 + ty * 2 + i) * NE + tx * 4] = o;
  }
}

// ---------------- routing: one wave per token ----------------
// grid TK/4 blocks x 256 threads (4 waves); wave handles token blockIdx*4+wave
__global__ __launch_bounds__(256) void route_kernel(const float* __restrict__ lp,
    int* __restrict__ cnt, float* __restrict__ Ppart,
    int* __restrict__ assign_row, float* __restrict__ gateA, int* __restrict__ destA,
    u16* __restrict__ Ybuf){
  const int wave = threadIdx.x >> 6, l = threadIdx.x & 63;
  const int t = blockIdx.x * 4 + wave;
  float v = lp[(size_t)t * NE + l] + lp[(size_t)TK * NE + (size_t)t * NE + l];
  // softmax over 64 lanes
  float m = v;
#pragma unroll
  for (int s = 32; s; s >>= 1){ float o = __shfl_xor(m, s); m = (o > m) ? o : m; }
  float ex = __expf(v - m);
  float ssum = ex;
#pragma unroll
  for (int s = 32; s; s >>= 1) ssum += __shfl_xor(ssum, s);
  float p = ex / ssum;
  // top-1 (tie -> lower index)
  float bv = p; int bi = l;
#pragma unroll
  for (int s = 32; s; s >>= 1){
    float ov = __shfl_xor(bv, s); int oi = __shfl_xor(bi, s);
    if (ov > bv || (ov == bv && oi < bi)){ bv = ov; bi = oi; }
  }
  int e1 = bi; float p1 = bv;
  float pmask = (l == e1) ? -1.f : p;
  bv = pmask; bi = l;
#pragma unroll
  for (int s = 32; s; s >>= 1){
    float ov = __shfl_xor(bv, s); int oi = __shfl_xor(bi, s);
    if (ov > bv || (ov == bv && oi < bi)){ bv = ov; bi = oi; }
  }
  int e2 = bi; float p2 = bv;
  int pos1 = 0, pos2 = 0;
  if (l == 0){
    pos1 = atomicAdd(&cnt[e1], 1);
    pos2 = atomicAdd(&cnt[e2], 1);
    if (pos1 < CAP){ int s1 = e1 * CAP + pos1; assign_row[s1] = t; gateA[s1] = p1; destA[s1] = 2 * t; }
    if (pos2 < CAP){ int s2 = e2 * CAP + pos2; assign_row[s2] = t; gateA[s2] = p2; destA[s2] = 2 * t + 1; }
  }
  pos1 = __shfl(pos1, 0);
  pos2 = __shfl(pos2, 0);
  if (pos1 >= CAP){   // dropped (rare): zero Ybuf row
    bf16x8 z = {0,0,0,0,0,0,0,0};
    *(bf16x8*)&Ybuf[(size_t)(2 * t) * HD + l * 16] = z;
    *(bf16x8*)&Ybuf[(size_t)(2 * t) * HD + l * 16 + 8] = z;
  }
  if (pos2 >= CAP){
    bf16x8 z = {0,0,0,0,0,0,0,0};
    *(bf16x8*)&Ybuf[(size_t)(2 * t + 1) * HD + l * 16] = z;
    *(bf16x8*)&Ybuf[(size_t)(2 * t + 1) * HD + l * 16 + 8] = z;
  }
  // per-block P partial (avoids 8192-deep global float atomics per address)
  __shared__ float sh[4][64];
  sh[wave][l] = p;
  __syncthreads();
  if (wave == 0)
    Ppart[(size_t)blockIdx.x * 64 + l] = sh[0][l] + sh[1][l] + sh[2][l] + sh[3][l];
}

// ---------------- MFMA GEMM: 128x128 tile, BK=32, global_load_lds staging ----------------
template<int MODE, int KDIM, int NDIM>
__global__ __launch_bounds__(256) void mfma_gemm(
    const u16* __restrict__ A, const u16* __restrict__ BT,
    u16* __restrict__ Obuf, float* __restrict__ outF,
    const int* __restrict__ cnt, const int* __restrict__ assign_row,
    const float* __restrict__ gate, const int* __restrict__ destIdx,
    const u16* __restrict__ Ybuf){
  const int e = (MODE == M_EXP1 || MODE == M_EXP2) ? blockIdx.z : 0;
  const int mbase = blockIdx.y * 128;
  const int nbase = blockIdx.x * 128;
  int count = 0;
  if (MODE == M_EXP1 || MODE == M_EXP2){
    count = cnt[e];
    if (mbase >= count) return;
  }
  __shared__ __align__(16) u16 As[128 * 32];
  __shared__ __align__(16) u16 Bs[128 * 32];
  const int tid = threadIdx.x;
  const int wave = tid >> 6, lane = tid & 63;
  const int wr = wave & 1, wc = wave >> 1;
  const int lm = lane & 15, quad = lane >> 4;
  const int l4r = lane >> 2;           // 0..15: row within 16-row group
  const int l4c = (lane & 3) * 8;      // u16 offset within 32-el k-stripe

  const size_t eoffB = (MODE == M_EXP1 || MODE == M_EXP2) ? (size_t)e * NDIM * KDIM : 0;
  const u16* agp[2]; const u16* bgp[2];
  u16* alp[2]; u16* blp[2];
#pragma unroll
  for (int it = 0; it < 2; it++){
    int ar = wave * 16 + it * 64 + l4r;   // row within 128-tile
    if (MODE == M_EXP1){
      int r = mbase + ar;
      int tok = (r < count) ? assign_row[e * CAP + r] : 0;
      agp[it] = A + (size_t)tok * KDIM + l4c;
    } else if (MODE == M_EXP2){
      agp[it] = A + ((size_t)e * CAP + mbase + ar) * KDIM + l4c;
    } else {
      agp[it] = A + (size_t)(mbase + ar) * KDIM + l4c;
    }
    bgp[it] = BT + eoffB + (size_t)(nbase + ar) * KDIM + l4c;
    alp[it] = As + (wave * 16 + it * 64) * 32;
    blp[it] = Bs + (wave * 16 + it * 64) * 32;
  }

  f32x4 acc[4][4];
#pragma unroll
  for (int mi = 0; mi < 4; mi++)
#pragma unroll
    for (int ni = 0; ni < 4; ni++)
      acc[mi][ni] = (f32x4){0.f, 0.f, 0.f, 0.f};

  for (int k0 = 0; k0 < KDIM; k0 += 32){
    gload_lds16(agp[0] + k0, alp[0]);
    gload_lds16(agp[1] + k0, alp[1]);
    gload_lds16(bgp[0] + k0, blp[0]);
    gload_lds16(bgp[1] + k0, blp[1]);
    __syncthreads();
    bf16x8 af[4], bfr[4];
#pragma unroll
    for (int mi = 0; mi < 4; mi++)
      af[mi] = *(const bf16x8*)&As[(wr * 64 + mi * 16 + lm) * 32 + quad * 8];
#pragma unroll
    for (int ni = 0; ni < 4; ni++)
      bfr[ni] = *(const bf16x8*)&Bs[(wc * 64 + ni * 16 + lm) * 32 + quad * 8];
#pragma unroll
    for (int mi = 0; mi < 4; mi++)
#pragma unroll
      for (int ni = 0; ni < 4; ni++)
        acc[mi][ni] = __builtin_amdgcn_mfma_f32_16x16x32_bf16(af[mi], bfr[ni], acc[mi][ni], 0, 0, 0);
    __syncthreads();
  }

  // epilogue: C/D layout col=lane&15, row=quad*4+reg
#pragma unroll
  for (int mi = 0; mi < 4; mi++){
#pragma unroll
    for (int i = 0; i < 4; i++){
      int r = mbase + wr * 64 + mi * 16 + quad * 4 + i;
      if ((MODE == M_EXP1 || MODE == M_EXP2) && r >= count) continue;
      u16* brow = nullptr;
      float* orow = nullptr;
      const u16 *yb0 = nullptr, *yb1 = nullptr;
      float g = 0.f;
      if (MODE == M_EXP1){
        brow = Obuf + ((size_t)e * CAP + r) * NDIM;
      } else if (MODE == M_EXP2){
        int d = destIdx[e * CAP + r];
        g = gate[e * CAP + r];
        brow = Obuf + (size_t)d * NDIM;
      } else if (MODE == M_SH1){
        brow = Obuf + (size_t)r * NDIM;
      } else {
        orow = outF + (size_t)r * NDIM;
        yb0 = Ybuf + (size_t)(2 * r) * NDIM;
        yb1 = Ybuf + (size_t)(2 * r + 1) * NDIM;
      }
#pragma unroll
      for (int ni = 0; ni < 4; ni++){
        int c = nbase + wc * 64 + ni * 16 + lm;
        float v = acc[mi][ni][i];
        if (MODE == M_EXP1)      brow[c] = f2bf(gelu_tanh(v));
        else if (MODE == M_EXP2) brow[c] = f2bf(g * v);
        else if (MODE == M_SH1)  brow[c] = f2bf(gelu_tanh(v));
        else                     orow[c] = v + bf2f(yb0[c]) + bf2f(yb1[c]);
      }
    }
  }
}

// ---------------- aux loss: reduce Ppart + cnt ----------------
__global__ __launch_bounds__(256) void aux_kernel(const int* __restrict__ cnt,
    const float* __restrict__ Ppart, float* __restrict__ out){
  const int l = threadIdx.x & 63, c = threadIdx.x >> 6;
  float s = 0.f;
  for (int b = c; b < TK / 4; b += 4) s += Ppart[(size_t)b * 64 + l];
  __shared__ float sh[4][64];
  sh[c][l] = s;
  __syncthreads();
  if (c == 0){
    float P = (sh[0][l] + sh[1][l] + sh[2][l] + sh[3][l]) * (1.0f / (float)TK);
    float f = (float)cnt[l] * (1.0f / (float)(TK * TOPK));
    float v = f * P;
#pragma unroll
    for (int s2 = 32; s2; s2 >>= 1) v += __shfl_xor(v, s2);
    if (l == 0) out[(size_t)TK * HD] = 0.64f * v;   // COEFF * E = 0.01 * 64
  }
}

extern "C" void kernel_launch(void* const* d_in, const int* in_sizes, int n_in,
                              void* d_out, int out_size, void* d_ws, size_t ws_size,
                              hipStream_t stream){
  const float* x   = (const float*)d_in[0];
  const float* wr  = (const float*)d_in[1];
  const float* w1  = (const float*)d_in[2];
  const float* w2  = (const float*)d_in[3];
  const float* ws1 = (const float*)d_in[4];
  const float* ws2 = (const float*)d_in[5];
  float* out = (float*)d_out;

  char* W = (char*)d_ws;
  size_t off = 0;
  auto alloc = [&](size_t b){ size_t o = off; off = (off + b + 255) & ~(size_t)255; return o; };
  u16*   xbf   = (u16*)(W + alloc((size_t)TK * HD * 2));
  u16*   w1T   = (u16*)(W + alloc((size_t)NE * FD * HD * 2));
  u16*   w2T   = (u16*)(W + alloc((size_t)NE * HD * FD * 2));
  u16*   ws1T  = (u16*)(W + alloc((size_t)HD * SFD * 2));
  u16*   ws2T  = (u16*)(W + alloc((size_t)SFD * HD * 2));
  u16*   Hbuf  = (u16*)(W + alloc((size_t)NE * CAP * FD * 2));
  u16*   Shb   = (u16*)(W + alloc((size_t)TK * SFD * 2));
  u16*   Ybuf  = (u16*)(W + alloc((size_t)TK * TOPK * HD * 2));
  float* lpart = (float*)(W + alloc((size_t)2 * TK * NE * 4));
  int*   assign_row = (int*)(W + alloc((size_t)NE * CAP * 4));
  float* gateA = (float*)(W + alloc((size_t)NE * CAP * 4));
  int*   destA = (int*)(W + alloc((size_t)NE * CAP * 4));
  float* Ppart = (float*)(W + alloc((size_t)(TK / 4) * 64 * 4));
  int*   cnt   = (int*)(W + alloc(256));

  hipMemsetAsync(cnt, 0, 256, stream);

  cast_x_kernel<<<dim3((TK * HD) / 1024), 256, 0, stream>>>(x, xbf);
  transpose_cast<<<dim3(FD / 64, HD / 64, NE), 256, 0, stream>>>(w1, w1T, HD, FD);
  transpose_cast<<<dim3(HD / 64, FD / 64, NE), 256, 0, stream>>>(w2, w2T, FD, HD);
  transpose_cast<<<dim3(SFD / 64, HD / 64, 1), 256, 0, stream>>>(ws1, ws1T, HD, SFD);
  transpose_cast<<<dim3(HD / 64, SFD / 64, 1), 256, 0, stream>>>(ws2, ws2T, SFD, HD);

  router_gemm<<<dim3(TK / 32, 2), 256, 0, stream>>>(x, wr, lpart);
  route_kernel<<<dim3(TK / 4), 256, 0, stream>>>(lpart, cnt, Ppart, assign_row, gateA, destA, Ybuf);

  mfma_gemm<M_EXP1, HD, FD><<<dim3(FD / 128, CAP / 128, NE), 256, 0, stream>>>(
      xbf, w1T, Hbuf, nullptr, cnt, assign_row, nullptr, nullptr, nullptr);
  mfma_gemm<M_EXP2, FD, HD><<<dim3(HD / 128, CAP / 128, NE), 256, 0, stream>>>(
      Hbuf, w2T, Ybuf, nullptr, cnt, nullptr, gateA, destA, nullptr);
  mfma_gemm<M_SH1, HD, SFD><<<dim3(SFD / 128, TK / 128, 1), 256, 0, stream>>>(
      xbf, ws1T, Shb, nullptr, nullptr, nullptr, nullptr, nullptr, nullptr);
  mfma_gemm<M_SH2, SFD, HD><<<dim3(HD / 128, TK / 128, 1), 256, 0, stream>>>(
      Shb, ws2T, nullptr, out, nullptr, nullptr, nullptr, nullptr, Ybuf);

  aux_kernel<<<dim3(1), 256, 0, stream>>>(cnt, Ppart, out);
}

// Round 3
// 721.167 us; speedup vs baseline: 1.2146x; 1.2146x over previous
//
#include <hip/hip_runtime.h>
#include <hip/hip_bf16.h>

#define TK 8192
#define HD 1024
#define NE 64
#define TOPK 2
#define CAP 1024
#define FD 512
#define SFD 1024

typedef unsigned short u16;
typedef unsigned int u32;
typedef short bf16x8 __attribute__((ext_vector_type(8)));
typedef float f32x4 __attribute__((ext_vector_type(4)));

#define M_EXP1 0
#define M_EXP2 1
#define M_SH1  2
#define M_SH2  3

__device__ __forceinline__ float bf2f(u16 b){
  u32 u = ((u32)b) << 16;
  return __uint_as_float(u);
}
__device__ __forceinline__ u16 f2bf(float f){
  u32 u = __float_as_uint(f);
  u32 r = (u + 0x7fffu + ((u >> 16) & 1u)) >> 16;
  return (u16)r;
}
__device__ __forceinline__ float gelu_tanh(float x){
  float x3 = x * x * x;
  float t = tanhf(0.7978845608028654f * (x + 0.044715f * x3));
  return 0.5f * x * (1.0f + t);
}

// async global->LDS, 16B per lane; LDS dest = wave-uniform base + lane*16
typedef __attribute__((address_space(1))) const u32 gu32;
typedef __attribute__((address_space(3))) u32 lu32;
__device__ __forceinline__ void gload_lds16(const void* g, void* l){
  gu32* gp = (gu32*)(unsigned long long)(uintptr_t)g;
  lu32* lp = (lu32*)(u32)(uintptr_t)l;
  __builtin_amdgcn_global_load_lds(gp, lp, 16, 0, 0);
}

// ---------------- prep: cast x to bf16 ----------------
__global__ __launch_bounds__(256) void cast_x_kernel(const float* __restrict__ x,
                                                     u16* __restrict__ xbf){
  size_t i = ((size_t)blockIdx.x * 256 + threadIdx.x) * 4;
  float4 v = *(const float4*)&x[i];
  ushort4 o;
  o.x = f2bf(v.x); o.y = f2bf(v.y); o.z = f2bf(v.z); o.w = f2bf(v.w);
  *(ushort4*)&xbf[i] = o;
}

// ---------------- prep: batched transpose fp32 [B,R,C] -> bf16 [B,C,R] ----------------
__global__ __launch_bounds__(256) void transpose_cast(const float* __restrict__ src,
                                                      u16* __restrict__ dst,
                                                      int R, int C){
  __shared__ float tile[64][65];
  const int c0 = blockIdx.x * 64, r0 = blockIdx.y * 64;
  const size_t bb = (size_t)blockIdx.z * R * C;
  const int tid = threadIdx.x;
  const int tr = tid >> 4, tc = (tid & 15) * 4;
#pragma unroll
  for (int i = 0; i < 4; i++){
    float4 v = *(const float4*)&src[bb + (size_t)(r0 + tr + i * 16) * C + c0 + tc];
    tile[tr + i * 16][tc + 0] = v.x;
    tile[tr + i * 16][tc + 1] = v.y;
    tile[tr + i * 16][tc + 2] = v.z;
    tile[tr + i * 16][tc + 3] = v.w;
  }
  __syncthreads();
#pragma unroll
  for (int i = 0; i < 4; i++){
    int dr = tr + i * 16;
    ushort4 o;
    o.x = f2bf(tile[tc + 0][dr]);
    o.y = f2bf(tile[tc + 1][dr]);
    o.z = f2bf(tile[tc + 2][dr]);
    o.w = f2bf(tile[tc + 3][dr]);
    *(ushort4*)&dst[bb + (size_t)(c0 + dr) * R + r0 + tc] = o;
  }
}

// ---------------- router GEMM (fp32, deterministic K-split partials) ----------------
__global__ __launch_bounds__(256) void router_gemm(const float* __restrict__ X,
                                                   const float* __restrict__ Wr,
                                                   float* __restrict__ part){
  __shared__ float Xs[32][36];
  __shared__ float Ws[32][64];
  const int t0 = blockIdx.x * 32;
  const int kh = blockIdx.y;
  const int tid = threadIdx.x;
  const int tx = tid & 15, ty = tid >> 4;
  float acc[2][4] = {};
  for (int k0 = kh * 512; k0 < kh * 512 + 512; k0 += 32){
    {
      int c = tid; int r = c >> 3, cc = (c & 7) * 4;
      *(float4*)&Xs[r][cc] = *(const float4*)&X[(size_t)(t0 + r) * HD + k0 + cc];
    }
#pragma unroll
    for (int i = 0; i < 2; i++){
      int c = tid + i * 256; int r = c >> 4, cc = (c & 15) * 4;
      *(float4*)&Ws[r][cc] = *(const float4*)&Wr[(size_t)(k0 + r) * NE + cc];
    }
    __syncthreads();
#pragma unroll
    for (int kk = 0; kk < 32; kk += 4){
      float a[2][4], b[4][4];
#pragma unroll
      for (int i = 0; i < 2; i++){
        float4 v = *(const float4*)&Xs[ty * 2 + i][kk];
        a[i][0] = v.x; a[i][1] = v.y; a[i][2] = v.z; a[i][3] = v.w;
      }
#pragma unroll
      for (int q = 0; q < 4; q++){
        float4 v = *(const float4*)&Ws[kk + q][tx * 4];
        b[q][0] = v.x; b[q][1] = v.y; b[q][2] = v.z; b[q][3] = v.w;
      }
#pragma unroll
      for (int i = 0; i < 2; i++)
#pragma unroll
        for (int j = 0; j < 4; j++)
          acc[i][j] += a[i][0]*b[0][j] + a[i][1]*b[1][j] + a[i][2]*b[2][j] + a[i][3]*b[3][j];
    }
    __syncthreads();
  }
#pragma unroll
  for (int i = 0; i < 2; i++){
    float4 o; o.x = acc[i][0]; o.y = acc[i][1]; o.z = acc[i][2]; o.w = acc[i][3];
    *(float4*)&part[(size_t)kh * TK * NE + (size_t)(t0 + ty * 2 + i) * NE + tx * 4] = o;
  }
}

// ---------------- routing: one wave per token ----------------
__global__ __launch_bounds__(256) void route_kernel(const float* __restrict__ lp,
    int* __restrict__ cnt, float* __restrict__ Ppart,
    int* __restrict__ assign_row, float* __restrict__ gateA, int* __restrict__ destA,
    u16* __restrict__ Ybuf){
  const int wave = threadIdx.x >> 6, l = threadIdx.x & 63;
  const int t = blockIdx.x * 4 + wave;
  float v = lp[(size_t)t * NE + l] + lp[(size_t)TK * NE + (size_t)t * NE + l];
  float m = v;
#pragma unroll
  for (int s = 32; s; s >>= 1){ float o = __shfl_xor(m, s); m = (o > m) ? o : m; }
  float ex = __expf(v - m);
  float ssum = ex;
#pragma unroll
  for (int s = 32; s; s >>= 1) ssum += __shfl_xor(ssum, s);
  float p = ex / ssum;
  float bv = p; int bi = l;
#pragma unroll
  for (int s = 32; s; s >>= 1){
    float ov = __shfl_xor(bv, s); int oi = __shfl_xor(bi, s);
    if (ov > bv || (ov == bv && oi < bi)){ bv = ov; bi = oi; }
  }
  int e1 = bi; float p1 = bv;
  float pmask = (l == e1) ? -1.f : p;
  bv = pmask; bi = l;
#pragma unroll
  for (int s = 32; s; s >>= 1){
    float ov = __shfl_xor(bv, s); int oi = __shfl_xor(bi, s);
    if (ov > bv || (ov == bv && oi < bi)){ bv = ov; bi = oi; }
  }
  int e2 = bi; float p2 = bv;
  int pos1 = 0, pos2 = 0;
  if (l == 0){
    pos1 = atomicAdd(&cnt[e1], 1);
    pos2 = atomicAdd(&cnt[e2], 1);
    if (pos1 < CAP){ int s1 = e1 * CAP + pos1; assign_row[s1] = t; gateA[s1] = p1; destA[s1] = 2 * t; }
    if (pos2 < CAP){ int s2 = e2 * CAP + pos2; assign_row[s2] = t; gateA[s2] = p2; destA[s2] = 2 * t + 1; }
  }
  pos1 = __shfl(pos1, 0);
  pos2 = __shfl(pos2, 0);
  if (pos1 >= CAP){   // dropped (rare): zero Ybuf row
    bf16x8 z = {0,0,0,0,0,0,0,0};
    *(bf16x8*)&Ybuf[(size_t)(2 * t) * HD + l * 16] = z;
    *(bf16x8*)&Ybuf[(size_t)(2 * t) * HD + l * 16 + 8] = z;
  }
  if (pos2 >= CAP){
    bf16x8 z = {0,0,0,0,0,0,0,0};
    *(bf16x8*)&Ybuf[(size_t)(2 * t + 1) * HD + l * 16] = z;
    *(bf16x8*)&Ybuf[(size_t)(2 * t + 1) * HD + l * 16 + 8] = z;
  }
  __shared__ float sh[4][64];
  sh[wave][l] = p;
  __syncthreads();
  if (wave == 0)
    Ppart[(size_t)blockIdx.x * 64 + l] = sh[0][l] + sh[1][l] + sh[2][l] + sh[3][l];
}

// ---------------- MFMA GEMM: 128x128 tile, BK=32, global_load_lds staging ----------------
template<int MODE, int KDIM, int NDIM>
__global__ __launch_bounds__(256) void mfma_gemm(
    const u16* __restrict__ A, const u16* __restrict__ BT,
    u16* __restrict__ Obuf, float* __restrict__ outF,
    const int* __restrict__ cnt, const int* __restrict__ assign_row,
    const float* __restrict__ gate, const int* __restrict__ destIdx,
    const u16* __restrict__ Ybuf){
  const int e = (MODE == M_EXP1 || MODE == M_EXP2) ? blockIdx.z : 0;
  const int mbase = blockIdx.y * 128;
  const int nbase = blockIdx.x * 128;
  int count = 0;
  if (MODE == M_EXP1 || MODE == M_EXP2){
    count = cnt[e];
    if (mbase >= count) return;
  }
  __shared__ __align__(16) u16 As[128 * 32];
  __shared__ __align__(16) u16 Bs[128 * 32];
  const int tid = threadIdx.x;
  const int wave = tid >> 6, lane = tid & 63;
  const int wr = wave & 1, wc = wave >> 1;
  const int lm = lane & 15, quad = lane >> 4;
  const int l4r = lane >> 2;
  const int l4c = (lane & 3) * 8;

  const size_t eoffB = (MODE == M_EXP1 || MODE == M_EXP2) ? (size_t)e * NDIM * KDIM : 0;
  const u16* agp[2]; const u16* bgp[2];
  u16* alp[2]; u16* blp[2];
#pragma unroll
  for (int it = 0; it < 2; it++){
    int ar = wave * 16 + it * 64 + l4r;
    if (MODE == M_EXP1){
      int r = mbase + ar;
      int tok = (r < count) ? assign_row[e * CAP + r] : 0;
      agp[it] = A + (size_t)tok * KDIM + l4c;
    } else if (MODE == M_EXP2){
      agp[it] = A + ((size_t)e * CAP + mbase + ar) * KDIM + l4c;
    } else {
      agp[it] = A + (size_t)(mbase + ar) * KDIM + l4c;
    }
    bgp[it] = BT + eoffB + (size_t)(nbase + ar) * KDIM + l4c;
    alp[it] = As + (wave * 16 + it * 64) * 32;
    blp[it] = Bs + (wave * 16 + it * 64) * 32;
  }

  f32x4 acc[4][4];
#pragma unroll
  for (int mi = 0; mi < 4; mi++)
#pragma unroll
    for (int ni = 0; ni < 4; ni++)
      acc[mi][ni] = (f32x4){0.f, 0.f, 0.f, 0.f};

  for (int k0 = 0; k0 < KDIM; k0 += 32){
    gload_lds16(agp[0] + k0, alp[0]);
    gload_lds16(agp[1] + k0, alp[1]);
    gload_lds16(bgp[0] + k0, blp[0]);
    gload_lds16(bgp[1] + k0, blp[1]);
    __syncthreads();
    bf16x8 af[4], bfr[4];
#pragma unroll
    for (int mi = 0; mi < 4; mi++)
      af[mi] = *(const bf16x8*)&As[(wr * 64 + mi * 16 + lm) * 32 + quad * 8];
#pragma unroll
    for (int ni = 0; ni < 4; ni++)
      bfr[ni] = *(const bf16x8*)&Bs[(wc * 64 + ni * 16 + lm) * 32 + quad * 8];
#pragma unroll
    for (int mi = 0; mi < 4; mi++)
#pragma unroll
      for (int ni = 0; ni < 4; ni++)
        acc[mi][ni] = __builtin_amdgcn_mfma_f32_16x16x32_bf16(af[mi], bfr[ni], acc[mi][ni], 0, 0, 0);
    __syncthreads();
  }

#pragma unroll
  for (int mi = 0; mi < 4; mi++){
#pragma unroll
    for (int i = 0; i < 4; i++){
      int r = mbase + wr * 64 + mi * 16 + quad * 4 + i;
      if ((MODE == M_EXP1 || MODE == M_EXP2) && r >= count) continue;
      u16* brow = nullptr;
      float* orow = nullptr;
      const u16 *yb0 = nullptr, *yb1 = nullptr;
      float g = 0.f;
      if (MODE == M_EXP1){
        brow = Obuf + ((size_t)e * CAP + r) * NDIM;
      } else if (MODE == M_EXP2){
        int d = destIdx[e * CAP + r];
        g = gate[e * CAP + r];
        brow = Obuf + (size_t)d * NDIM;
      } else if (MODE == M_SH1){
        brow = Obuf + (size_t)r * NDIM;
      } else {
        orow = outF + (size_t)r * NDIM;
        yb0 = Ybuf + (size_t)(2 * r) * NDIM;
        yb1 = Ybuf + (size_t)(2 * r + 1) * NDIM;
      }
#pragma unroll
      for (int ni = 0; ni < 4; ni++){
        int c = nbase + wc * 64 + ni * 16 + lm;
        float v = acc[mi][ni][i];
        if (MODE == M_EXP1)      brow[c] = f2bf(gelu_tanh(v));
        else if (MODE == M_EXP2) brow[c] = f2bf(g * v);
        else if (MODE == M_SH1)  brow[c] = f2bf(gelu_tanh(v));
        else                     orow[c] = v + bf2f(yb0[c]) + bf2f(yb1[c]);
      }
    }
  }
}

// ---------------- aux stage 1: reduce Ppart[2048][64] -> P1[64][64] ----------------
__global__ __launch_bounds__(256) void aux1_kernel(const float* __restrict__ Ppart,
                                                   float* __restrict__ P1){
  const int l = threadIdx.x & 63, w = threadIdx.x >> 6;
  const int r0 = blockIdx.x * 32;
  float s = 0.f;
#pragma unroll
  for (int j = 0; j < 8; j++)
    s += Ppart[(size_t)(r0 + w + 4 * j) * 64 + l];
  __shared__ float sh[4][64];
  sh[w][l] = s;
  __syncthreads();
  if (w == 0)
    P1[(size_t)blockIdx.x * 64 + l] = sh[0][l] + sh[1][l] + sh[2][l] + sh[3][l];
}

// ---------------- aux stage 2: reduce P1[64][64], emit loss ----------------
__global__ __launch_bounds__(256) void aux2_kernel(const int* __restrict__ cnt,
    const float* __restrict__ P1, float* __restrict__ out){
  const int l = threadIdx.x & 63, w = threadIdx.x >> 6;
  float s = 0.f;
#pragma unroll
  for (int j = 0; j < 16; j++)
    s += P1[(size_t)(w + 4 * j) * 64 + l];
  __shared__ float sh[4][64];
  sh[w][l] = s;
  __syncthreads();
  if (w == 0){
    float P = (sh[0][l] + sh[1][l] + sh[2][l] + sh[3][l]) * (1.0f / (float)TK);
    float f = (float)cnt[l] * (1.0f / (float)(TK * TOPK));
    float v = f * P;
#pragma unroll
    for (int s2 = 32; s2; s2 >>= 1) v += __shfl_xor(v, s2);
    if (l == 0) out[(size_t)TK * HD] = 0.64f * v;   // COEFF * E = 0.01 * 64
  }
}

extern "C" void kernel_launch(void* const* d_in, const int* in_sizes, int n_in,
                              void* d_out, int out_size, void* d_ws, size_t ws_size,
                              hipStream_t stream){
  const float* x   = (const float*)d_in[0];
  const float* wr  = (const float*)d_in[1];
  const float* w1  = (const float*)d_in[2];
  const float* w2  = (const float*)d_in[3];
  const float* ws1 = (const float*)d_in[4];
  const float* ws2 = (const float*)d_in[5];
  float* out = (float*)d_out;

  char* W = (char*)d_ws;
  size_t off = 0;
  auto alloc = [&](size_t b){ size_t o = off; off = (off + b + 255) & ~(size_t)255; return o; };
  u16*   xbf   = (u16*)(W + alloc((size_t)TK * HD * 2));
  u16*   w1T   = (u16*)(W + alloc((size_t)NE * FD * HD * 2));
  u16*   w2T   = (u16*)(W + alloc((size_t)NE * HD * FD * 2));
  u16*   ws1T  = (u16*)(W + alloc((size_t)HD * SFD * 2));
  u16*   ws2T  = (u16*)(W + alloc((size_t)SFD * HD * 2));
  u16*   Hbuf  = (u16*)(W + alloc((size_t)NE * CAP * FD * 2));
  u16*   Shb   = (u16*)(W + alloc((size_t)TK * SFD * 2));
  u16*   Ybuf  = (u16*)(W + alloc((size_t)TK * TOPK * HD * 2));
  float* lpart = (float*)(W + alloc((size_t)2 * TK * NE * 4));
  int*   assign_row = (int*)(W + alloc((size_t)NE * CAP * 4));
  float* gateA = (float*)(W + alloc((size_t)NE * CAP * 4));
  int*   destA = (int*)(W + alloc((size_t)NE * CAP * 4));
  float* Ppart = (float*)(W + alloc((size_t)(TK / 4) * 64 * 4));
  float* P1    = (float*)(W + alloc((size_t)64 * 64 * 4));
  int*   cnt   = (int*)(W + alloc(256));

  hipMemsetAsync(cnt, 0, 256, stream);

  cast_x_kernel<<<dim3((TK * HD) / 1024), 256, 0, stream>>>(x, xbf);
  transpose_cast<<<dim3(FD / 64, HD / 64, NE), 256, 0, stream>>>(w1, w1T, HD, FD);
  transpose_cast<<<dim3(HD / 64, FD / 64, NE), 256, 0, stream>>>(w2, w2T, FD, HD);
  transpose_cast<<<dim3(SFD / 64, HD / 64, 1), 256, 0, stream>>>(ws1, ws1T, HD, SFD);
  transpose_cast<<<dim3(HD / 64, SFD / 64, 1), 256, 0, stream>>>(ws2, ws2T, SFD, HD);

  router_gemm<<<dim3(TK / 32, 2), 256, 0, stream>>>(x, wr, lpart);
  route_kernel<<<dim3(TK / 4), 256, 0, stream>>>(lpart, cnt, Ppart, assign_row, gateA, destA, Ybuf);

  mfma_gemm<M_EXP1, HD, FD><<<dim3(FD / 128, CAP / 128, NE), 256, 0, stream>>>(
      xbf, w1T, Hbuf, nullptr, cnt, assign_row, nullptr, nullptr, nullptr);
  mfma_gemm<M_EXP2, FD, HD><<<dim3(HD / 128, CAP / 128, NE), 256, 0, stream>>>(
      Hbuf, w2T, Ybuf, nullptr, cnt, nullptr, gateA, destA, nullptr);
  mfma_gemm<M_SH1, HD, SFD><<<dim3(SFD / 128, TK / 128, 1), 256, 0, stream>>>(
      xbf, ws1T, Shb, nullptr, nullptr, nullptr, nullptr, nullptr, nullptr);
  mfma_gemm<M_SH2, SFD, HD><<<dim3(HD / 128, TK / 128, 1), 256, 0, stream>>>(
      Shb, ws2T, nullptr, out, nullptr, nullptr, nullptr, nullptr, Ybuf);

  aux1_kernel<<<dim3(64), 256, 0, stream>>>(Ppart, P1);
  aux2_kernel<<<dim3(1), 256, 0, stream>>>(cnt, P1, out);
}